// Round 12
// baseline (15.027 us; speedup 1.0000x reference)
//
#include <hip/hip_runtime.h>

#define L 4096
#define NT 128                // threads per block (2 waves), one block per row
#define C 32                  // elements per thread (one chunk per thread)
#define NCC (NT + 2)          // chunk rows incl. 1 pad each side
#define SS 36                 // scan row stride in words (144B: 16B-aligned, 8-phase banks)
#define MAXR 256

typedef unsigned int u32;

static __device__ __forceinline__ u32 umax(u32 a, u32 b) { return a > b ? a : b; }

// One block per row. Exact greedy NMS via iterative local-max peeling.
// u32 key = bits(|x|)+1 (0 = inactive). Chunk width 32 <= MIN_DIST+1 =>
// only a chunk's FIRST argmax can win, and its +-32 window is exactly
// suffix(om) of chunk cc-1 + own chunk + prefix(om) of chunk cc+1:
//   blocked-left  iff sfx[cc-1][om] >= k   (earlier index wins ties)
//   blocked-right iff pfx[cc+1][om] >  k
// Two-phase round (detect | barrier | apply | barrier) — the minimal
// winner->rescan->detect propagation structure. Scans rewritten only when
// a chunk's alive set changes; grouped uint4 writes keep VGPR pressure low.

#define SCANS_OUT()                                                       \
    do {                                                                  \
        u32* pr_ = &pfxS[cc * SS];                                        \
        u32* sr_ = &sfxS[cc * SS];                                        \
        u32 p_ = 0, nom_ = 0;                                             \
        _Pragma("unroll")                                                 \
        for (int g_ = 0; g_ < C; g_ += 4) {                               \
            u32 t0_, t1_, t2_, t3_;                                       \
            u32 k_;                                                       \
            k_ = key[g_ + 0]; if (k_ > p_) { p_ = k_; nom_ = g_ + 0; } t0_ = p_; \
            k_ = key[g_ + 1]; if (k_ > p_) { p_ = k_; nom_ = g_ + 1; } t1_ = p_; \
            k_ = key[g_ + 2]; if (k_ > p_) { p_ = k_; nom_ = g_ + 2; } t2_ = p_; \
            k_ = key[g_ + 3]; if (k_ > p_) { p_ = k_; nom_ = g_ + 3; } t3_ = p_; \
            *reinterpret_cast<uint4*>(pr_ + g_) = make_uint4(t0_, t1_, t2_, t3_); \
        }                                                                 \
        u32 s_ = 0;                                                       \
        _Pragma("unroll")                                                 \
        for (int g_ = C - 4; g_ >= 0; g_ -= 4) {                          \
            u32 t3_ = umax(s_, key[g_ + 3]);                              \
            u32 t2_ = umax(t3_, key[g_ + 2]);                             \
            u32 t1_ = umax(t2_, key[g_ + 1]);                             \
            u32 t0_ = umax(t1_, key[g_ + 0]);                             \
            *reinterpret_cast<uint4*>(sr_ + g_) = make_uint4(t0_, t1_, t2_, t3_); \
            s_ = t0_;                                                     \
        }                                                                 \
        run = p_; om = nom_;                                              \
    } while (0)

__global__ __launch_bounds__(NT) void extrema_nms_kernel(const float* __restrict__ in,
                                                         float* __restrict__ out) {
    __shared__ u32 pfxS[NCC * SS];
    __shared__ u32 sfxS[NCC * SS];
    __shared__ u32 winmF[2 * NCC];   // winner masks, double-buffered by parity
    __shared__ int flagsF[2];

    const int tid = threadIdx.x;
    const int cc = tid + 1;
    const int base = tid * C;
    const float* xrow = in + (size_t)blockIdx.x * L;

    // ---- pads (written once, never again) ----
    if (tid < 2 * SS) {                        // scan pad rows 0 and NCC-1
        int row = (tid < SS) ? 0 : (NCC - 1);
        int col = tid % SS;
        pfxS[row * SS + col] = 0;
        sfxS[row * SS + col] = 0;
    }
    if (tid < 4) {                             // winm pads, both parities
        int slot = ((tid & 1) ? (NCC - 1) : 0) + ((tid >> 1) ? NCC : 0);
        winmF[slot] = 0;
    }
    if (tid == 0) { flagsF[0] = 0; flagsF[1] = 0; }

    // ---- streaming key computation (x not kept in registers) ----
    // right[i] = (i<L-1) && x[i+1] >  x[i]; left[i] = (i==0) || x[i] <= x[i-1]
    u32 key[C];
    {
        float xm1 = (tid > 0) ? xrow[base - 1] : 0.0f;
        float xpC = (base + C < L) ? xrow[base + C] : 0.0f;
        float4 cur = *reinterpret_cast<const float4*>(xrow + base);
        float prev = xm1;
        #pragma unroll
        for (int g = 0; g < C / 4; ++g) {
            float4 nxt;
            if (g < C / 4 - 1) nxt = *reinterpret_cast<const float4*>(xrow + base + 4 * (g + 1));
            else nxt = make_float4(xpC, 0.f, 0.f, 0.f);
            float e0 = cur.x, e1 = cur.y, e2 = cur.z, e3 = cur.w;
            float pv[4] = {prev, e0, e1, e2};
            float cv[4] = {e0, e1, e2, e3};
            float nv[4] = {e1, e2, e3, nxt.x};
            #pragma unroll
            for (int j = 0; j < 4; ++j) {
                int i = base + 4 * g + j;
                float xi = cv[j];
                bool right = (i < L - 1) && (nv[j] > xi);
                bool left  = (i == 0) || (xi <= pv[j]);
                bool neg   = (xi <= 0.0f);
                bool ext = (right && left && neg) || (!right && !left && !neg);
                key[4 * g + j] = ext ? ((__float_as_uint(xi) & 0x7fffffffu) + 1u) : 0u;
            }
            prev = e3; cur = nxt;
        }
    }

    // ---- initial alive mask + scans -> LDS ----
    u32 alivem = 0;
    #pragma unroll
    for (int o = 0; o < C; ++o) if (key[o]) alivem |= (1u << o);
    u32 run, om;
    SCANS_OUT();
    u32 keptm = 0;
    __syncthreads();

    // ---- peeling rounds: 2 barriers per round (structural minimum) ----
    for (int r = 0; r < MAXR; ++r) {
        // ===== detect: only the chunk's first argmax can win =====
        u32 wm = 0;
        if (run) {
            u32 bL = sfxS[(cc - 1) * SS + om];   // blocks iff >= run
            u32 bR = pfxS[(cc + 1) * SS + om];   // blocks iff >  run
            if (bL < run && bR <= run) wm = 1u << om;
        }
        winmF[(r & 1) * NCC + cc] = wm;          // unconditional: no stale masks
        if (wm) { keptm |= wm; flagsF[r & 1] = 1; }   // same-value race benign
        __syncthreads();

        // ===== apply winners =====
        int go = flagsF[r & 1];
        u32 mL = 0, mR = 0;
        if (run) {
            const int pp = (r & 1) * NCC;
            mL = winmF[pp + cc - 1];
            mR = winmF[pp + cc + 1];
        }
        if (tid == 0) flagsF[(r + 1) & 1] = 0;   // safe: 2 barriers since last read
        if (!go) break;                          // uniform: fixpoint reached
        if (run) {
            u32 supmask = 0;
            if (wm) {
                supmask = 0xffffffffu;           // own winner: whole chunk dies
            } else {
                // left-chunk winner at q kills own [0..q]; right-chunk at q kills [q..31]
                if (mL) { int q = __ffs((int)mL) - 1; supmask |= (2u << q) - 1u; }
                if (mR) { int q = __ffs((int)mR) - 1; supmask |= ~((1u << q) - 1u); }
            }
            u32 nA = alivem & ~supmask;
            if (nA != alivem) {                  // keys actually change
                alivem = nA;
                if (nA == 0) {                   // full death: zero-store fast path
                    uint4 z = make_uint4(0, 0, 0, 0);
                    u32* pr = &pfxS[cc * SS];
                    u32* sr = &sfxS[cc * SS];
                    #pragma unroll
                    for (int q4 = 0; q4 < C; q4 += 4) {
                        *reinterpret_cast<uint4*>(pr + q4) = z;
                        *reinterpret_cast<uint4*>(sr + q4) = z;
                    }
                    run = 0;
                } else {
                    #pragma unroll
                    for (int o = 0; o < C; ++o)
                        key[o] = ((supmask >> o) & 1u) ? 0u : key[o];
                    SCANS_OUT();
                }
            }
        }
        __syncthreads();
    }

    // ---- output: re-read x (L2-hot), mask by kept bits ----
    float* orow = out + (size_t)blockIdx.x * L;
    #pragma unroll
    for (int g = 0; g < C / 4; ++g) {
        float4 f = *reinterpret_cast<const float4*>(xrow + base + 4 * g);
        f.x = ((keptm >> (4 * g + 0)) & 1u) ? f.x : 0.0f;
        f.y = ((keptm >> (4 * g + 1)) & 1u) ? f.y : 0.0f;
        f.z = ((keptm >> (4 * g + 2)) & 1u) ? f.z : 0.0f;
        f.w = ((keptm >> (4 * g + 3)) & 1u) ? f.w : 0.0f;
        *reinterpret_cast<float4*>(orow + base + 4 * g) = f;
    }
}

extern "C" void kernel_launch(void* const* d_in, const int* in_sizes, int n_in,
                              void* d_out, int out_size, void* d_ws, size_t ws_size,
                              hipStream_t stream) {
    const float* in = (const float*)d_in[0];
    float* out = (float*)d_out;
    int rows = in_sizes[0] / L;   // 128
    extrema_nms_kernel<<<rows, NT, 0, stream>>>(in, out);
}